// Round 7
// baseline (5284.404 us; speedup 1.0000x reference)
//
#include <hip/hip_runtime.h>
#include <hip/hip_bf16.h>

#define BATCH 64
#define SEQ   512
#define ISZ   1024
#define HID   1024
#define OUTSEQ_ELEMS (BATCH * SEQ * HID)   // 33554432

typedef float f32x4 __attribute__((ext_vector_type(4)));
typedef short bf16x8 __attribute__((ext_vector_type(8)));

__device__ __forceinline__ unsigned short f2bf(float f) {
    union { float f; unsigned u; } v; v.f = f;
    unsigned r = v.u + 0x7fffu + ((v.u >> 16) & 1u);   // RNE
    return (unsigned short)(r >> 16);
}

// ---------------------------------------------------------------------------
// Kernel A: xp[m][n] = input[m][:] . Wx[:][n] + b[n]  -> written into d_out.
// (unchanged since R1 — proven, ~180 us)
// ---------------------------------------------------------------------------
__global__ __launch_bounds__(256)
void xproj_gemm(const float* __restrict__ A, const float* __restrict__ W,
                const float* __restrict__ bias, float* __restrict__ C)
{
    __shared__ __align__(16) unsigned short As[128][72];
    __shared__ __align__(16) unsigned short Bs[128][72];
    const int tid  = threadIdx.x;
    const int lane = tid & 63;
    const int wave = tid >> 6;
    const int m0 = blockIdx.y * 128;
    const int n0 = blockIdx.x * 128;
    const int wm = (wave >> 1) * 64;
    const int wn = (wave & 1) * 64;
    const int l15 = lane & 15;
    const int kq8 = (lane >> 4) * 8;

    f32x4 acc[4][4] = {};

    for (int k0 = 0; k0 < ISZ; k0 += 64) {
        #pragma unroll
        for (int i = 0; i < 8; ++i) {
            int idx = tid + i * 256;
            int row = idx >> 4;
            int kq  = idx & 15;
            float4 v = *reinterpret_cast<const float4*>(
                A + (size_t)(m0 + row) * ISZ + k0 + kq * 4);
            unsigned short* dst = &As[row][kq * 4];
            dst[0] = f2bf(v.x); dst[1] = f2bf(v.y);
            dst[2] = f2bf(v.z); dst[3] = f2bf(v.w);
        }
        #pragma unroll
        for (int i = 0; i < 8; ++i) {
            int idx = tid + i * 256;
            int kk = idx >> 5;
            int nq = idx & 31;
            float4 v = *reinterpret_cast<const float4*>(
                W + (size_t)(k0 + kk) * HID + n0 + nq * 4);
            Bs[nq * 4 + 0][kk] = f2bf(v.x);
            Bs[nq * 4 + 1][kk] = f2bf(v.y);
            Bs[nq * 4 + 2][kk] = f2bf(v.z);
            Bs[nq * 4 + 3][kk] = f2bf(v.w);
        }
        __syncthreads();
        #pragma unroll
        for (int kk = 0; kk < 64; kk += 32) {
            const int krd = kk + kq8;
            bf16x8 a[4], b[4];
            #pragma unroll
            for (int mf = 0; mf < 4; ++mf)
                a[mf] = *reinterpret_cast<const bf16x8*>(&As[wm + mf * 16 + l15][krd]);
            #pragma unroll
            for (int nf = 0; nf < 4; ++nf)
                b[nf] = *reinterpret_cast<const bf16x8*>(&Bs[wn + nf * 16 + l15][krd]);
            #pragma unroll
            for (int mf = 0; mf < 4; ++mf)
                #pragma unroll
                for (int nf = 0; nf < 4; ++nf)
                    acc[mf][nf] = __builtin_amdgcn_mfma_f32_16x16x32_bf16(
                        a[mf], b[nf], acc[mf][nf], 0, 0, 0);
        }
        __syncthreads();
    }

    const int r4 = (lane >> 4) * 4;
    #pragma unroll
    for (int nf = 0; nf < 4; ++nf) {
        int col = n0 + wn + nf * 16 + l15;
        float bv = bias[col];
        #pragma unroll
        for (int mf = 0; mf < 4; ++mf) {
            int row = m0 + wm + mf * 16 + r4;
            #pragma unroll
            for (int r = 0; r < 4; ++r)
                C[(size_t)(row + r) * HID + col] = acc[mf][nf][r] + bv;
        }
    }
}

// ---------------------------------------------------------------------------
// prep: WhT[c][k] = bf16(Wh[k][c]) — one-time 2 MB transpose so step kernels
// can load B fragments as contiguous bf16x8.
// ---------------------------------------------------------------------------
__global__ __launch_bounds__(256)
void prep_whT(const float* __restrict__ W, unsigned short* __restrict__ WhT)
{
    __shared__ unsigned short T[64][72];
    const int tid = threadIdx.x;
    const int k0 = blockIdx.y * 64, c0 = blockIdx.x * 64;
    #pragma unroll
    for (int p = 0; p < 4; ++p) {
        int k = p * 16 + (tid >> 4);
        int c = (tid & 15) * 4;
        float4 v = *reinterpret_cast<const float4*>(
            W + (size_t)(ISZ + k0 + k) * HID + c0 + c);
        T[c + 0][k] = f2bf(v.x); T[c + 1][k] = f2bf(v.y);
        T[c + 2][k] = f2bf(v.z); T[c + 3][k] = f2bf(v.w);
    }
    __syncthreads();
    {
        int c  = tid >> 2;
        int k4 = (tid & 3) * 16;
        bf16x8 a = *reinterpret_cast<const bf16x8*>(&T[c][k4]);
        bf16x8 b = *reinterpret_cast<const bf16x8*>(&T[c][k4 + 8]);
        *reinterpret_cast<bf16x8*>(WhT + (size_t)(c0 + c) * HID + k0 + k4)     = a;
        *reinterpret_cast<bf16x8*>(WhT + (size_t)(c0 + c) * HID + k0 + k4 + 8) = b;
    }
}

// ---------------------------------------------------------------------------
// init: hA = bf16(h_0)
// ---------------------------------------------------------------------------
__global__ __launch_bounds__(256)
void init_h(const float* __restrict__ h0, unsigned short* __restrict__ h)
{
    int i = blockIdx.x * 256 + threadIdx.x;
    float4 v = *reinterpret_cast<const float4*>(h0 + (size_t)i * 4);
    unsigned long long d =  (unsigned long long)f2bf(v.x)
                         | ((unsigned long long)f2bf(v.y) << 16)
                         | ((unsigned long long)f2bf(v.z) << 32)
                         | ((unsigned long long)f2bf(v.w) << 48);
    *reinterpret_cast<unsigned long long*>(h + (size_t)i * 4) = d;
}

// ---------------------------------------------------------------------------
// One recurrence step as its own kernel: h_t = tanh(xp_t + h_{t-1} @ Wh).
// Coherence between steps comes from the kernel boundary (no fences/flags).
// 64 blocks x 256 thr; block owns 16 cols; wave = 16-batch M-tile (R2 map).
// Frag loads straight from global (WhT/h are L2/IC-resident), depth-2 pipe.
// ---------------------------------------------------------------------------
#define LOADR(Adst, Bdst, R)                                                    \
    {                                                                           \
        _Pragma("unroll") for (int i = 0; i < 8; ++i) {                         \
            Adst[i] = *reinterpret_cast<const bf16x8*>(ap + (R) * 256 + i * 32);\
            Bdst[i] = *reinterpret_cast<const bf16x8*>(bp + (R) * 256 + i * 32);\
        }                                                                       \
    }
#define MFMAR(As, Bs)                                                           \
    {                                                                           \
        ac0 = __builtin_amdgcn_mfma_f32_16x16x32_bf16(As[0], Bs[0], ac0, 0, 0, 0); \
        ac1 = __builtin_amdgcn_mfma_f32_16x16x32_bf16(As[1], Bs[1], ac1, 0, 0, 0); \
        ac2 = __builtin_amdgcn_mfma_f32_16x16x32_bf16(As[2], Bs[2], ac2, 0, 0, 0); \
        ac3 = __builtin_amdgcn_mfma_f32_16x16x32_bf16(As[3], Bs[3], ac3, 0, 0, 0); \
        ac0 = __builtin_amdgcn_mfma_f32_16x16x32_bf16(As[4], Bs[4], ac0, 0, 0, 0); \
        ac1 = __builtin_amdgcn_mfma_f32_16x16x32_bf16(As[5], Bs[5], ac1, 0, 0, 0); \
        ac2 = __builtin_amdgcn_mfma_f32_16x16x32_bf16(As[6], Bs[6], ac2, 0, 0, 0); \
        ac3 = __builtin_amdgcn_mfma_f32_16x16x32_bf16(As[7], Bs[7], ac3, 0, 0, 0); \
    }

__global__ __launch_bounds__(256)
void rnn_step(const unsigned short* __restrict__ WhT,
              const unsigned short* __restrict__ hprev,
              unsigned short* __restrict__ hnext,
              float* __restrict__ out, int t, int last)
{
    const int tid  = threadIdx.x;
    const int lane = tid & 63;
    const int wave = tid >> 6;
    const int c0   = blockIdx.x * 16;
    const int l15  = lane & 15;
    const int kq8  = (lane >> 4) * 8;
    const int arow = wave * 16 + l15;          // A row (batch)
    const int bcol = c0 + l15;                 // B col (hidden)
    const unsigned short* ap = hprev + (size_t)arow * HID + kq8;
    const unsigned short* bp = WhT   + (size_t)bcol * HID + kq8;
    const int orow = wave * 16 + (lane >> 4) * 4;
    const int ocol = bcol;

    float xpv[4];
    #pragma unroll
    for (int j = 0; j < 4; ++j)
        xpv[j] = out[(size_t)(orow + j) * (SEQ * HID) + (size_t)t * HID + ocol];

    bf16x8 Aa[8], Ba[8], Ab[8], Bb[8];
    f32x4 ac0 = {}, ac1 = {}, ac2 = {}, ac3 = {};

    LOADR(Aa, Ba, 0);
    LOADR(Ab, Bb, 1);
    MFMAR(Aa, Ba);
    LOADR(Aa, Ba, 2);
    MFMAR(Ab, Bb);
    LOADR(Ab, Bb, 3);
    MFMAR(Aa, Ba);
    MFMAR(Ab, Bb);

    f32x4 acc = (ac0 + ac1) + (ac2 + ac3);

    #pragma unroll
    for (int j = 0; j < 4; ++j) {
        float hv = tanhf(acc[j] + xpv[j]);
        out[(size_t)(orow + j) * (SEQ * HID) + (size_t)t * HID + ocol] = hv;
        hnext[(size_t)(orow + j) * HID + ocol] = f2bf(hv);
        if (last)
            out[(size_t)OUTSEQ_ELEMS + (size_t)(orow + j) * HID + ocol] = hv;
    }
}

extern "C" void kernel_launch(void* const* d_in, const int* in_sizes, int n_in,
                              void* d_out, int out_size, void* d_ws, size_t ws_size,
                              hipStream_t stream)
{
    const float* input = (const float*)d_in[0];
    const float* h0    = (const float*)d_in[1];
    const float* W     = (const float*)d_in[2];
    const float* bias  = (const float*)d_in[3];
    float* out = (float*)d_out;

    unsigned short* WhT = (unsigned short*)d_ws;              // 2 MB
    unsigned short* hA  = WhT + (size_t)HID * HID;            // 128 KB
    unsigned short* hB  = hA + (size_t)BATCH * HID;           // 128 KB

    dim3 gA(HID / 128, (BATCH * SEQ) / 128);   // (8, 256)
    xproj_gemm<<<gA, dim3(256), 0, stream>>>(input, W, bias, out);
    prep_whT<<<dim3(16, 16), dim3(256), 0, stream>>>(W, WhT);
    init_h<<<dim3(64), dim3(256), 0, stream>>>(h0, hA);

    unsigned short* cur = hA;
    unsigned short* nxt = hB;
    for (int t = 0; t < SEQ; ++t) {
        rnn_step<<<dim3(64), dim3(256), 0, stream>>>(WhT, cur, nxt, out, t,
                                                     t == SEQ - 1 ? 1 : 0);
        unsigned short* tmp = cur; cur = nxt; nxt = tmp;
    }
}